// Round 13
// baseline (192.374 us; speedup 1.0000x reference)
//
#include <hip/hip_runtime.h>

// WL_DiffNet bf16-MFMA, round 13:
//   gather3: 16B/lane row-pair gather (halved memory instructions), scalar pk,
//     full occupancy, no LDS/barriers.
//   mega8: unchanged GEMM (512,4), barrier-free k-loop, frag-major weights.
//     Final-depth mode: no F' store, no phase-2 -- in-register row-sum +
//     shfl_xor reduce + atomicAdd into d_out (zeroed by prep each call).
//   prep: hb2 + pkk + wpk1 + wpk2 + zrow + out-zero fused in one launch.
// 9 launches total (was 14). K order unchanged -> absmax ~0.0625.

#define BB 64
#define NN 512
#define MAXNB 10
#define HH 256
#define ROWS (BB*NN)   // 32768
#define BM 64          // mega rows per block
#define ZROW 32768     // zero row index in G/Hb2 buffers

typedef __attribute__((ext_vector_type(8))) short bf16x8;
typedef __attribute__((ext_vector_type(4))) float f32x4;
typedef unsigned short u16;
typedef unsigned int u32;
typedef __attribute__((address_space(3))) u32 lds_u32;
typedef __attribute__((address_space(1))) const u32 glb_u32;

__device__ __forceinline__ u16 f2b(float f) {   // rne f32->bf16
    union { float f; u32 u; } v; v.f = f;
    u32 r = v.u + 0x7FFF + ((v.u >> 16) & 1);
    return (u16)(r >> 16);
}
__device__ __forceinline__ float b2f(u32 u) {   // low 16 bits -> f32
    union { u32 u; float f; } v; v.u = u << 16; return v.f;
}
__device__ __forceinline__ float b2fh(u32 u) {  // high 16 bits -> f32
    union { u32 u; float f; } v; v.u = u & 0xffff0000u; return v.f;
}
__device__ __forceinline__ void gl16(const u16* g, u16* l) {
    __builtin_amdgcn_global_load_lds((glb_u32*)g, (lds_u32*)l, 16, 0, 0);
}
// XCD-bijective swizzle (nwg % 8 == 0)
__device__ __forceinline__ int xcd_swz(int bid, int nwg) {
    return (bid & 7) * (nwg >> 3) + (bid >> 3);
}

// ---- castk: f32 -> bf16 bulk cast ---------------------------------------

__global__ __launch_bounds__(256) void castk(const float* __restrict__ in,
                                             u16* __restrict__ out) {
    int i = blockIdx.x * 256 + threadIdx.x;
    float4 v = ((const float4*)in)[i];
    u32 a = f2b(v.x) | ((u32)f2b(v.y) << 16);
    u32 b = f2b(v.z) | ((u32)f2b(v.w) << 16);
    ((uint2*)out)[i] = make_uint2(a, b);
}

// ---- prep: hb2 | pkk | wpk1 | wpk2 | zrow | out-zero (branch by blockIdx) -

__global__ __launch_bounds__(256) void prep(const float* __restrict__ bond,
                                            const float* __restrict__ W2,
                                            const float* __restrict__ b2,
                                            u16* __restrict__ Hb2,
                                            const int* __restrict__ agr,
                                            const int* __restrict__ bgr,
                                            const int* __restrict__ nnb,
                                            u32* __restrict__ pk,
                                            const float* __restrict__ W1,
                                            u16* __restrict__ Wp1,
                                            u16* __restrict__ Wp2,
                                            u16* __restrict__ G0,
                                            u16* __restrict__ G1,
                                            float* __restrict__ osum) {
    int b = blockIdx.x, tid = threadIdx.x;
    if (b < 4096) {                       // hb2: rows b*8 .. +8
        int c = tid, r0 = b * 8;
        float w[5];
#pragma unroll
        for (int f = 0; f < 5; ++f) w[f] = W2[(size_t)(HH + f) * HH + c];
        float bb = b2[c];
        for (int r = r0; r < r0 + 8; ++r) {
            float s = bb;
#pragma unroll
            for (int f = 0; f < 5; ++f) s += bond[r * 5 + f] * w[f];
            Hb2[(size_t)r * HH + c] = f2b(s);
        }
    } else if (b < 5376) {                // pkk: t < 327680
        int t = (b - 4096) * 256 + tid;
        int r = t / 10, k = t - r * 10;
        int brow = (r >> 9) << 9;
        bool valid = (k < nnb[r]);
        u32 pA = valid ? (u32)(brow + agr[t * 2 + 1]) : (u32)ZROW;
        u32 pB = valid ? (u32)(brow + bgr[t * 2 + 1]) : (u32)ZROW;
        pk[t] = pA | (pB << 16);
    } else if (b < 5888) {                // wpk1: W1 [512x256] -> Wp1
        int o = (b - 5376) * 256 + tid;
        int e = o & 7, lane = (o >> 3) & 63, nq = (o >> 9) & 15, kt = o >> 13;
        int k = kt * 32 + (lane >> 4) * 8 + e;
        int n = nq * 16 + (lane & 15);
        Wp1[o] = f2b(W1[(size_t)k * HH + n]);
    } else if (b < 6144) {                // wpk2: W2a [256x256] -> Wp2
        int o = (b - 5888) * 256 + tid;
        int e = o & 7, lane = (o >> 3) & 63, nq = (o >> 9) & 15, kt = o >> 13;
        int k = kt * 32 + (lane >> 4) * 8 + e;
        int n = nq * 16 + (lane & 15);
        Wp2[o] = f2b(W2[(size_t)k * HH + n]);
    } else if (b == 6144) {               // zrow
        G0[(size_t)ZROW * 256 + tid] = 0;
        G1[(size_t)ZROW * 256 + tid] = 0;
        Hb2[(size_t)ZROW * 256 + tid] = 0;
    } else {                              // zero d_out: 16384 floats, 64 blocks
        int i = (b - 6145) * 256 + tid;
        osum[i] = 0.f;
    }
}

// ---- gather3: 16B/lane row-pair gather -----------------------------------
// 256 thr x 2048 blocks (8 blocks/CU, 32 waves/CU). Wave q: rows base+q*4..+4
// as 2 pairs; lane half h selects row of pair, sl = 16B slot (32 per row).

__global__ __launch_bounds__(256, 8) void gather3(const u16* __restrict__ Gall,
                                                  const u16* __restrict__ Hall,
                                                  const u32* __restrict__ pk,
                                                  u16* __restrict__ Nsg) {
    int tid = threadIdx.x;
    int base = xcd_swz(blockIdx.x, gridDim.x) * 16;
    int q = tid >> 6, lane = tid & 63;
    int h = lane >> 5, sl = lane & 31;
    const u32* pkr = pk + ((size_t)base + q * 4) * 10;

#pragma unroll
    for (int j = 0; j < 2; ++j) {         // pair j: local rows 2j, 2j+1
        float s0 = 0.f, s1 = 0.f, s2 = 0.f, s3 = 0.f;
        float s4 = 0.f, s5 = 0.f, s6 = 0.f, s7 = 0.f;
#pragma unroll
        for (int k = 0; k < MAXNB; ++k) {
            u32 p0 = (u32)__builtin_amdgcn_readfirstlane((int)pkr[(2 * j) * 10 + k]);
            u32 p1 = (u32)__builtin_amdgcn_readfirstlane((int)pkr[(2 * j + 1) * 10 + k]);
            u32 pa = h ? p1 : p0;
            const uint4* ga4 = (const uint4*)(Gall + (size_t)(pa & 0xffffu) * 256) + sl;
            const uint4* hb4 = (const uint4*)(Hall + (size_t)(pa >> 16) * 256) + sl;
            uint4 a = *ga4, c = *hb4;
            s0 += fmaxf(b2f(a.x)  + b2f(c.x),  0.f);
            s1 += fmaxf(b2fh(a.x) + b2fh(c.x), 0.f);
            s2 += fmaxf(b2f(a.y)  + b2f(c.y),  0.f);
            s3 += fmaxf(b2fh(a.y) + b2fh(c.y), 0.f);
            s4 += fmaxf(b2f(a.z)  + b2f(c.z),  0.f);
            s5 += fmaxf(b2fh(a.z) + b2fh(c.z), 0.f);
            s6 += fmaxf(b2f(a.w)  + b2f(c.w),  0.f);
            s7 += fmaxf(b2fh(a.w) + b2fh(c.w), 0.f);
        }
        u32 o0 = f2b(s0) | ((u32)f2b(s1) << 16);
        u32 o1 = f2b(s2) | ((u32)f2b(s3) << 16);
        u32 o2 = f2b(s4) | ((u32)f2b(s5) << 16);
        u32 o3 = f2b(s6) | ((u32)f2b(s7) << 16);
        ((uint4*)(Nsg + (size_t)(base + q * 4 + 2 * j + h) * 256))[sl] =
            make_uint4(o0, o1, o2, o3);
    }
}

// ---- mega8: GEMM; final-depth mode reduces to d_out via atomics ----------
// 512 thr, 8 waves; wave wc owns cols wc*32..+32, all 64 rows.
// LDS 64KB: A_ (F -> F') + N_ (N). launch_bounds(512,4): VGPR<=128.

__global__ __launch_bounds__(512, 4) void mega8(const u16* __restrict__ Fbf,
                                                const u16* __restrict__ Nsg,
                                                const u16* __restrict__ Wp1,
                                                const float* __restrict__ b1,
                                                const u16* __restrict__ Wp2,
                                                u16* __restrict__ Fout,
                                                u16* __restrict__ Gout,
                                                float* __restrict__ osum) {
    __shared__ u16 A_[BM * 256];   // 32KB  (F -> F')
    __shared__ u16 N_[BM * 256];   // 32KB  (N)

    int tid = threadIdx.x;
    int base = xcd_swz(blockIdx.x, gridDim.x) * BM;
    int lane = tid & 63, wid = tid >> 6;
    int wc = wid, m = lane & 15, g = lane >> 4;

    auto stage = [&](u16* dst, const u16* src) {   // 64 rows x 512B, pre-swz src
#pragma unroll
        for (int q = 0; q < 4; ++q) {
            int c = (wid * 4 + q) * 64 + lane;
            int r = c >> 5, ph = c & 31;
            gl16(src + (size_t)r * 256 + (ph ^ (r & 7)) * 8,
                 dst + (wid * 4 + q) * 512);
        }
    };
    auto ldw = [&](const u16* Wp, int kt, int j) {
        return *(const uint4*)(Wp + ((size_t)(kt * 16 + wc * 2 + j) * 64 + lane) * 8);
    };
    auto step = [&](const u16* Ar, int kslot, f32x4 (&ac)[4][2],
                    const uint4& b0, const uint4& b1v) {
        int asl = kslot * 4 + g;
        bf16x8 bb0 = *(const bf16x8*)&b0, bb1 = *(const bf16x8*)&b1v;
#pragma unroll
        for (int mi = 0; mi < 4; ++mi) {
            int r = mi * 16 + m;
            bf16x8 af = *(const bf16x8*)(Ar + r * 256 + ((asl ^ (r & 7)) * 8));
            ac[mi][0] = __builtin_amdgcn_mfma_f32_16x16x32_bf16(af, bb0, ac[mi][0], 0, 0, 0);
            ac[mi][1] = __builtin_amdgcn_mfma_f32_16x16x32_bf16(af, bb1, ac[mi][1], 0, 0, 0);
        }
    };

    stage(A_, Fbf + (size_t)base * 256);
    if (Wp1) stage(N_, Nsg + (size_t)base * 256);
    const u16* Wp0 = Wp1 ? Wp1 : Wp2;
    uint4 bE0 = ldw(Wp0, 0, 0), bE1 = ldw(Wp0, 0, 1);
    uint4 bO0 = ldw(Wp0, 1, 0), bO1 = ldw(Wp0, 1, 1);
    __syncthreads();   // B1: tiles staged

    if (Wp1) {
        f32x4 acc[4][2];
#pragma unroll
        for (int mi = 0; mi < 4; ++mi)
#pragma unroll
            for (int j = 0; j < 2; ++j) acc[mi][j] = (f32x4){0.f, 0.f, 0.f, 0.f};

        // phase-1a: kt 0..7 (A_ = F), barrier-free, 2-deep B prefetch
#pragma unroll
        for (int kt = 0; kt < 8; kt += 2) {
            step(A_, kt, acc, bE0, bE1);
            bE0 = ldw(Wp1, kt + 2, 0); bE1 = ldw(Wp1, kt + 2, 1);
            step(A_, kt + 1, acc, bO0, bO1);
            bO0 = ldw(Wp1, kt + 3, 0); bO1 = ldw(Wp1, kt + 3, 1);
        }
        // phase-1b: kt 8..15 (N_)
#pragma unroll
        for (int kt = 8; kt < 16; kt += 2) {
            step(N_, kt & 7, acc, bE0, bE1);
            if (kt + 2 < 16)  { bE0 = ldw(Wp1, kt + 2, 0); bE1 = ldw(Wp1, kt + 2, 1); }
            else if (Gout)    { bE0 = ldw(Wp2, 0, 0);      bE1 = ldw(Wp2, 0, 1); }
            step(N_, (kt + 1) & 7, acc, bO0, bO1);
            if (kt + 3 < 16)  { bO0 = ldw(Wp1, kt + 3, 0); bO1 = ldw(Wp1, kt + 3, 1); }
            else if (Gout)    { bO0 = ldw(Wp2, 1, 0);      bO1 = ldw(Wp2, 1, 1); }
        }

        if (osum) {
            // final depth: relu(acc+b1), sum rows in-register, reduce over g,
            // one atomicAdd per (block, col). No F' store, no phase-2.
            int b = base >> 9;
#pragma unroll
            for (int j = 0; j < 2; ++j) {
                int col = wc * 32 + j * 16 + m;
                float bb = b1[col];
                float s = 0.f;
#pragma unroll
                for (int mi = 0; mi < 4; ++mi)
#pragma unroll
                    for (int rr = 0; rr < 4; ++rr)
                        s += fmaxf(acc[mi][j][rr] + bb, 0.f);
                s += __shfl_xor(s, 16);
                s += __shfl_xor(s, 32);
                if (g == 0) atomicAdd(osum + b * 256 + col, s);
            }
            return;
        }

        __syncthreads();   // B2: all waves done reading A_

        // F' = relu(acc+b1) -> A_ (swizzled)
#pragma unroll
        for (int mi = 0; mi < 4; ++mi)
#pragma unroll
            for (int j = 0; j < 2; ++j) {
                int col = wc * 32 + j * 16 + m;
                float bb = b1[col];
#pragma unroll
                for (int rr = 0; rr < 4; ++rr) {
                    int r = mi * 16 + g * 4 + rr;
                    A_[r * 256 + ((col >> 3) ^ (r & 7)) * 8 + (col & 7)] =
                        f2b(fmaxf(acc[mi][j][rr] + bb, 0.f));
                }
            }
        __syncthreads();   // B3: F' visible

        // coalesced F' store
#pragma unroll
        for (int i = 0; i < 4; ++i) {
            int c = tid + i * 512;
            int r = c >> 5, ph = c & 31;
            uint4 v = ((const uint4*)A_)[r * 32 + ph];
            ((uint4*)(Fout + (size_t)(base + r) * 256))[ph ^ (r & 7)] = v;
        }
    }

    if (!Gout) return;

    // phase-2: G' = A_(F' or F) @ W2a, K=256 (bE/bO hold Wp2 kt0,kt1)
    f32x4 gacc[4][2];
#pragma unroll
    for (int mi = 0; mi < 4; ++mi)
#pragma unroll
        for (int j = 0; j < 2; ++j) gacc[mi][j] = (f32x4){0.f, 0.f, 0.f, 0.f};

#pragma unroll
    for (int kt = 0; kt < 8; kt += 2) {
        step(A_, kt, gacc, bE0, bE1);
        if (kt + 2 < 8) { bE0 = ldw(Wp2, kt + 2, 0); bE1 = ldw(Wp2, kt + 2, 1); }
        step(A_, kt + 1, gacc, bO0, bO1);
        if (kt + 3 < 8) { bO0 = ldw(Wp2, kt + 3, 0); bO1 = ldw(Wp2, kt + 3, 1); }
    }

    // direct G' store (plain row-major)
#pragma unroll
    for (int mi = 0; mi < 4; ++mi)
#pragma unroll
        for (int j = 0; j < 2; ++j) {
            int col = wc * 32 + j * 16 + m;
#pragma unroll
            for (int rr = 0; rr < 4; ++rr) {
                int r = mi * 16 + g * 4 + rr;
                Gout[(size_t)(base + r) * 256 + col] = f2b(gacc[mi][j][rr]);
            }
        }
}

extern "C" void kernel_launch(void* const* d_in, const int* in_sizes, int n_in,
                              void* d_out, int out_size, void* d_ws, size_t ws_size,
                              hipStream_t stream) {
    const float* input_bond    = (const float*)d_in[1];
    const int*   atom_graph    = (const int*)d_in[2];
    const int*   bond_graph    = (const int*)d_in[3];
    const int*   num_nbs       = (const int*)d_in[4];
    const float* atom_features = (const float*)d_in[5];
    const float* W2 = (const float*)d_in[6];
    const float* b2 = (const float*)d_in[7];
    const float* W1 = (const float*)d_in[8];
    const float* b1 = (const float*)d_in[9];
    float* out = (float*)d_out;

    char* w = (char*)d_ws;
    u16* f0  = (u16*)w;                          // 16MB
    u16* f1  = (u16*)(w + ((size_t)16 << 20));   // 16MB
    u16* G0  = (u16*)(w + ((size_t)32 << 20));   // 16MB + zero row
    u16* G1  = (u16*)(w + ((size_t)49 << 20));   // 16MB + zero row
    u16* Hb2 = (u16*)(w + ((size_t)66 << 20));   // 16MB + zero row
    u16* Nsg = (u16*)(w + ((size_t)83 << 20));   // 16MB
    u16* Wp1 = (u16*)(w + ((size_t)99 << 20));            // 256KB
    u16* Wp2 = (u16*)(w + ((size_t)99 << 20) + (512 << 10)); // 128KB
    u32* pk  = (u32*)(w + ((size_t)100 << 20));  // 1.25MB

    castk<<<ROWS * HH / 1024, 256, 0, stream>>>(atom_features, f0);
    prep<<<6209, 256, 0, stream>>>(input_bond, W2, b2, Hb2, atom_graph,
                                   bond_graph, num_nbs, pk, W1, Wp1, Wp2,
                                   G0, G1, out);

    // G0 = F0 @ W2a  (skip-mode)
    mega8<<<ROWS / BM, 512, 0, stream>>>(f0, nullptr, nullptr, nullptr, Wp2,
                                         nullptr, G0, nullptr);
    // depth 0
    gather3<<<ROWS / 16, 256, 0, stream>>>(G0, Hb2, pk, Nsg);
    mega8<<<ROWS / BM, 512, 0, stream>>>(f0, Nsg, Wp1, b1, Wp2, f1, G1, nullptr);
    // depth 1
    gather3<<<ROWS / 16, 256, 0, stream>>>(G1, Hb2, pk, Nsg);
    mega8<<<ROWS / BM, 512, 0, stream>>>(f1, Nsg, Wp1, b1, Wp2, f0, G0, nullptr);
    // depth 2 (final: fused row-sum -> d_out, no F'/G' stores)
    gather3<<<ROWS / 16, 256, 0, stream>>>(G0, Hb2, pk, Nsg);
    mega8<<<ROWS / BM, 512, 0, stream>>>(f0, Nsg, Wp1, b1, Wp2, nullptr,
                                         nullptr, out);
}

// Round 15
// 149.326 us; speedup vs baseline: 1.2883x; 1.2883x over previous
//
#include <hip/hip_runtime.h>

// WL_DiffNet, round 15: round-14 fp16 pipeline + gather pk-index fix.
//   Round-14 bug: pkr pre-offset by (base + wid*8) but indexed by
//   r*10+k with r = wid*8+i -> double wid*8 offset; waves 1-7 gathered
//   wrong rows. Fix: index pkr[i*10+k] (local).
//   - fp16 pipeline (10 mantissa bits > bf16's 7; N(0,1) scale, no overflow)
//   - gather math packed: v_pk_add_f16/v_pk_max_f16, no unpack/cvt
//   - MFMA: mfma_f32_16x16x32_f16 (same fragment layout as bf16)
//   - final depth: fused row-sum + shfl reduce + atomicAdd into d_out
// Structure, swizzles, barriers identical to round 9 (best measured: 160us).

#define BB 64
#define NN 512
#define MAXNB 10
#define HH 256
#define ROWS (BB*NN)   // 32768
#define BM 64          // rows per block
#define ZROW 32768     // zero row index in G/Hb2 buffers

typedef _Float16 f16x8 __attribute__((ext_vector_type(8)));
typedef _Float16 h2 __attribute__((ext_vector_type(2)));
typedef __attribute__((ext_vector_type(4))) float f32x4;
typedef unsigned short u16;
typedef unsigned int u32;
typedef __attribute__((address_space(3))) u32 lds_u32;
typedef __attribute__((address_space(1))) const u32 glb_u32;

union U32H2 { u32 u; h2 h; };

__device__ __forceinline__ u16 f2h(float f) {   // rne f32->f16
    union { _Float16 h; u16 u; } v; v.h = (_Float16)f; return v.u;
}
__device__ __forceinline__ void gl16(const u16* g, u16* l) {
    __builtin_amdgcn_global_load_lds((glb_u32*)g, (lds_u32*)l, 16, 0, 0);
}
// XCD-bijective swizzle (nwg % 8 == 0)
__device__ __forceinline__ int xcd_swz(int bid, int nwg) {
    return (bid & 7) * (nwg >> 3) + (bid >> 3);
}

// ---- one-time prep -------------------------------------------------------

__global__ __launch_bounds__(256) void castk(const float* __restrict__ in,
                                             u16* __restrict__ out) {
    int i = blockIdx.x * 256 + threadIdx.x;
    float4 v = ((const float4*)in)[i];
    u32 a = f2h(v.x) | ((u32)f2h(v.y) << 16);
    u32 b = f2h(v.z) | ((u32)f2h(v.w) << 16);
    ((uint2*)out)[i] = make_uint2(a, b);
}

__global__ __launch_bounds__(256) void hb2_kernel(const float* __restrict__ bond,
                                                  const float* __restrict__ W2,
                                                  const float* __restrict__ b2,
                                                  u16* __restrict__ Hb2) {
    int c = threadIdx.x;
    int r0 = blockIdx.x * 8;
    float w[5];
#pragma unroll
    for (int f = 0; f < 5; ++f) w[f] = W2[(size_t)(HH + f) * HH + c];
    float bb = b2[c];
    for (int r = r0; r < r0 + 8; ++r) {
        float s = bb;
#pragma unroll
        for (int f = 0; f < 5; ++f) s += bond[r * 5 + f] * w[f];
        Hb2[(size_t)r * HH + c] = f2h(s);
    }
}

// pk[t] = absrowA | absrowB<<16; invalid -> ZROW (zeroed row)
__global__ __launch_bounds__(256) void pkk(const int* __restrict__ agr,
                                           const int* __restrict__ bgr,
                                           const int* __restrict__ nnb,
                                           u32* __restrict__ pk) {
    int t = blockIdx.x * 256 + threadIdx.x;   // < 327680
    int r = t / 10, k = t - r * 10;
    int brow = (r >> 9) << 9;
    bool valid = (k < nnb[r]);
    u32 pA = valid ? (u32)(brow + agr[t * 2 + 1]) : (u32)ZROW;
    u32 pB = valid ? (u32)(brow + bgr[t * 2 + 1]) : (u32)ZROW;
    pk[t] = pA | (pB << 16);
}

// fragment-major weight pack: Wp[((kt*16+nq)*64+lane)*8 + e] =
//   f16(W[(kt*32 + (lane>>4)*8 + e) * 256 + nq*16 + (lane&15)])
__global__ __launch_bounds__(256) void wpk(const float* __restrict__ W,
                                           u16* __restrict__ Wp) {
    int o = blockIdx.x * 256 + threadIdx.x;
    int e = o & 7, lane = (o >> 3) & 63, nq = (o >> 9) & 15, kt = o >> 13;
    int k = kt * 32 + (lane >> 4) * 8 + e;
    int n = nq * 16 + (lane & 15);
    Wp[o] = f2h(W[(size_t)k * HH + n]);
}

// block 0: zero row ZROW of G0/G1/Hb2; blocks 1..64: zero d_out
__global__ __launch_bounds__(256) void zrow(u16* G0, u16* G1, u16* Hb2,
                                            float* osum) {
    int b = blockIdx.x, t = threadIdx.x;
    if (b == 0) {
        G0[(size_t)ZROW * 256 + t] = 0;
        G1[(size_t)ZROW * 256 + t] = 0;
        Hb2[(size_t)ZROW * 256 + t] = 0;
    } else {
        osum[(b - 1) * 256 + t] = 0.f;
    }
}

// ---- mega: fused gather + [F|N]@W1 + F'@W2a, barrier-free k-loop ---------
// 512 thr, 8 waves; wave wc owns cols wc*32..+32, all 64 rows.
// LDS 64KB: A_ (F -> F') + N_ (N -> G'). B direct from packed W, reg-prefetch.

__global__ __launch_bounds__(512, 4) void mega(const u16* __restrict__ Fh,
                                               const u16* __restrict__ Gall,
                                               const u16* __restrict__ Hall,
                                               const u32* __restrict__ pk,
                                               const u16* __restrict__ Wp1,
                                               const float* __restrict__ b1,
                                               const u16* __restrict__ Wp2,
                                               u16* __restrict__ Fout,
                                               u16* __restrict__ Gout,
                                               float* __restrict__ osum) {
    __shared__ u16 A_[BM * 256];   // 32KB
    __shared__ u16 N_[BM * 256];   // 32KB

    int tid = threadIdx.x;
    int base = xcd_swz(blockIdx.x, gridDim.x) * BM;
    int lane = tid & 63, wid = tid >> 6;
    int wc = wid, m = lane & 15, g = lane >> 4;

    // stage F -> A_ (async, pre-swizzled source / linear dest)
#pragma unroll
    for (int q = 0; q < 4; ++q) {
        int c = (wid * 4 + q) * 64 + lane;
        int r = c >> 5, ph = c & 31;
        gl16(Fh + (size_t)(base + r) * 256 + (ph ^ (r & 7)) * 8,
             A_ + (wid * 4 + q) * 512);
    }

    uint4 breg[2];

    if (Wp1) {
        // fused gather: wave rows wid*8..+8; lane = uint2 col-slot (4 fp16)
        const uint2* Gb = (const uint2*)Gall;
        const uint2* Hb = (const uint2*)Hall;
        const u32* pkr = pk + ((size_t)base + wid * 8) * 10;   // wave base
        h2 zz = (h2)(_Float16)0;
#pragma unroll
        for (int i = 0; i < 8; ++i) {
            int r = wid * 8 + i;
            h2 accA = zz, accB = zz;
#pragma unroll
            for (int k = 0; k < MAXNB; ++k) {
                u32 p = pkr[i * 10 + k];   // LOCAL index (round-14 bug: r*10+k)
                uint2 ga = Gb[(size_t)(p & 0xffffu) * 64 + lane];
                uint2 hb = Hb[(size_t)(p >> 16) * 64 + lane];
                U32H2 ax{ga.x}, ay{ga.y}, cx{hb.x}, cy{hb.y};
                accA += __builtin_elementwise_max(ax.h + cx.h, zz);
                accB += __builtin_elementwise_max(ay.h + cy.h, zz);
            }
            U32H2 oa, ob; oa.h = accA; ob.h = accB;
            int s16 = (lane >> 1) ^ (r & 7);
            *(uint2*)(N_ + r * 256 + s16 * 8 + (lane & 1) * 4) =
                make_uint2(oa.u, ob.u);
        }

        // prefetch B kt0
#pragma unroll
        for (int j = 0; j < 2; ++j)
            breg[j] = *(const uint4*)(Wp1 + ((size_t)(wc * 2 + j) * 64 + lane) * 8);
        __syncthreads();   // B1: stageA (all waves) + N_ writes visible

        f32x4 acc[4][2];
#pragma unroll
        for (int mi = 0; mi < 4; ++mi)
#pragma unroll
            for (int j = 0; j < 2; ++j) acc[mi][j] = (f32x4){0.f, 0.f, 0.f, 0.f};

        // phase-1: K=512, 16 kt, BARRIER-FREE; A from A_ (kt<8) or N_ (kt>=8)
        for (int kt = 0; kt < 16; ++kt) {
            f16x8 bcur[2];
            bcur[0] = *(f16x8*)&breg[0];
            bcur[1] = *(f16x8*)&breg[1];
            if (kt < 15) {
#pragma unroll
                for (int j = 0; j < 2; ++j)
                    breg[j] = *(const uint4*)(Wp1 +
                        ((size_t)((kt + 1) * 16 + wc * 2 + j) * 64 + lane) * 8);
            } else if (Gout) {
#pragma unroll
                for (int j = 0; j < 2; ++j)
                    breg[j] = *(const uint4*)(Wp2 +
                        ((size_t)(wc * 2 + j) * 64 + lane) * 8);
            }
            const u16* Ar = (kt < 8) ? A_ : N_;
            int asl = (kt & 7) * 4 + g;
            f16x8 af[4];
#pragma unroll
            for (int mi = 0; mi < 4; ++mi) {
                int r = mi * 16 + m;
                af[mi] = *(const f16x8*)(Ar + r * 256 + ((asl ^ (r & 7)) * 8));
            }
#pragma unroll
            for (int mi = 0; mi < 4; ++mi)
#pragma unroll
                for (int j = 0; j < 2; ++j)
                    acc[mi][j] = __builtin_amdgcn_mfma_f32_16x16x32_f16(
                        af[mi], bcur[j], acc[mi][j], 0, 0, 0);
        }

        if (osum) {
            // final depth: relu(acc+b1), in-register row-sum, reduce over g,
            // one atomicAdd per (block, col). No F' store, no phase-2.
            int b = base >> 9;
#pragma unroll
            for (int j = 0; j < 2; ++j) {
                int col = wc * 32 + j * 16 + m;
                float bb = b1[col];
                float s = 0.f;
#pragma unroll
                for (int mi = 0; mi < 4; ++mi)
#pragma unroll
                    for (int rr = 0; rr < 4; ++rr)
                        s += fmaxf(acc[mi][j][rr] + bb, 0.f);
                s += __shfl_xor(s, 16);
                s += __shfl_xor(s, 32);
                if (g == 0) atomicAdd(osum + b * 256 + col, s);
            }
            return;
        }

        __syncthreads();   // B2: all waves done reading A_/N_

        // F' = relu(acc+b1) -> A_ (F dead)
#pragma unroll
        for (int mi = 0; mi < 4; ++mi)
#pragma unroll
            for (int j = 0; j < 2; ++j) {
                int col = wc * 32 + j * 16 + m;
                float bb = b1[col];
#pragma unroll
                for (int rr = 0; rr < 4; ++rr) {
                    int r = mi * 16 + g * 4 + rr;
                    A_[r * 256 + ((col >> 3) ^ (r & 7)) * 8 + (col & 7)] =
                        f2h(fmaxf(acc[mi][j][rr] + bb, 0.f));
                }
            }
        __syncthreads();   // B3: F' visible

        // coalesced F' store
#pragma unroll
        for (int i = 0; i < 4; ++i) {
            int c = tid + i * 512;
            int r = c >> 5, ph = c & 31;
            uint4 v = ((const uint4*)A_)[r * 32 + ph];
            ((uint4*)(Fout + (size_t)(base + r) * 256))[ph ^ (r & 7)] = v;
        }
    } else {
        // skip-mode: A_ <- F; prefetch Wp2 kt0
        if (Gout) {
#pragma unroll
            for (int j = 0; j < 2; ++j)
                breg[j] = *(const uint4*)(Wp2 + ((size_t)(wc * 2 + j) * 64 + lane) * 8);
        }
        __syncthreads();   // B1
    }

    if (!Gout) return;

    // phase-2: G' = A_(F' or F) @ W2a, K=256, 8 kt, BARRIER-FREE
    f32x4 gacc[4][2];
#pragma unroll
    for (int mi = 0; mi < 4; ++mi)
#pragma unroll
        for (int j = 0; j < 2; ++j) gacc[mi][j] = (f32x4){0.f, 0.f, 0.f, 0.f};

    for (int kt = 0; kt < 8; ++kt) {
        f16x8 bcur[2];
        bcur[0] = *(f16x8*)&breg[0];
        bcur[1] = *(f16x8*)&breg[1];
        if (kt < 7) {
#pragma unroll
            for (int j = 0; j < 2; ++j)
                breg[j] = *(const uint4*)(Wp2 +
                    ((size_t)((kt + 1) * 16 + wc * 2 + j) * 64 + lane) * 8);
        }
        int asl = kt * 4 + g;
        f16x8 af[4];
#pragma unroll
        for (int mi = 0; mi < 4; ++mi) {
            int r = mi * 16 + m;
            af[mi] = *(const f16x8*)(A_ + r * 256 + ((asl ^ (r & 7)) * 8));
        }
#pragma unroll
        for (int mi = 0; mi < 4; ++mi)
#pragma unroll
            for (int j = 0; j < 2; ++j)
                gacc[mi][j] = __builtin_amdgcn_mfma_f32_16x16x32_f16(
                    af[mi], bcur[j], gacc[mi][j], 0, 0, 0);
    }

    // G' -> N_ bounce (N dead), then coalesced store
#pragma unroll
    for (int mi = 0; mi < 4; ++mi)
#pragma unroll
        for (int j = 0; j < 2; ++j) {
            int col = wc * 32 + j * 16 + m;
#pragma unroll
            for (int rr = 0; rr < 4; ++rr) {
                int r = mi * 16 + g * 4 + rr;
                N_[r * 256 + ((col >> 3) ^ (r & 7)) * 8 + (col & 7)] =
                    f2h(gacc[mi][j][rr]);
            }
        }
    __syncthreads();   // B4: G' visible
#pragma unroll
    for (int i = 0; i < 4; ++i) {
        int c = tid + i * 512;
        int r = c >> 5, ph = c & 31;
        uint4 v = ((const uint4*)N_)[r * 32 + ph];
        ((uint4*)(Gout + (size_t)(base + r) * 256))[ph ^ (r & 7)] = v;
    }
}

extern "C" void kernel_launch(void* const* d_in, const int* in_sizes, int n_in,
                              void* d_out, int out_size, void* d_ws, size_t ws_size,
                              hipStream_t stream) {
    const float* input_bond    = (const float*)d_in[1];
    const int*   atom_graph    = (const int*)d_in[2];
    const int*   bond_graph    = (const int*)d_in[3];
    const int*   num_nbs       = (const int*)d_in[4];
    const float* atom_features = (const float*)d_in[5];
    const float* W2 = (const float*)d_in[6];
    const float* b2 = (const float*)d_in[7];
    const float* W1 = (const float*)d_in[8];
    const float* b1 = (const float*)d_in[9];
    float* out = (float*)d_out;

    char* w = (char*)d_ws;
    u16* f0  = (u16*)w;                          // 16MB
    u16* f1  = (u16*)(w + ((size_t)16 << 20));   // 16MB
    u16* G0  = (u16*)(w + ((size_t)32 << 20));   // 16MB + zero row
    u16* G1  = (u16*)(w + ((size_t)49 << 20));   // 16MB + zero row
    u16* Hb2 = (u16*)(w + ((size_t)66 << 20));   // 16MB + zero row
    u16* Wp1 = (u16*)(w + ((size_t)83 << 20));            // 256KB
    u16* Wp2 = (u16*)(w + ((size_t)83 << 20) + (512 << 10)); // 128KB
    u32* pk  = (u32*)(w + ((size_t)84 << 20));   // 1.25MB

    castk<<<ROWS * HH / 1024, 256, 0, stream>>>(atom_features, f0);
    hb2_kernel<<<ROWS / 8, 256, 0, stream>>>(input_bond, W2, b2, Hb2);
    pkk<<<ROWS * MAXNB / 256, 256, 0, stream>>>(atom_graph, bond_graph, num_nbs, pk);
    wpk<<<512, 256, 0, stream>>>(W1, Wp1);   // kt 0..15
    wpk<<<256, 256, 0, stream>>>(W2, Wp2);   // kt 0..7 (W2a part)
    zrow<<<65, 256, 0, stream>>>(G0, G1, Hb2, out);

    // G0 = F0 @ W2a  (skip-mode)
    mega<<<ROWS / BM, 512, 0, stream>>>(f0, nullptr, nullptr, nullptr,
                                        nullptr, nullptr, Wp2, nullptr, G0,
                                        nullptr);
    // depth 0..2 (G ping-pong; final depth: fused row-sum -> d_out)
    mega<<<ROWS / BM, 512, 0, stream>>>(f0, G0, Hb2, pk, Wp1, b1, Wp2, f1, G1,
                                        nullptr);
    mega<<<ROWS / BM, 512, 0, stream>>>(f1, G1, Hb2, pk, Wp1, b1, Wp2, f0, G0,
                                        nullptr);
    mega<<<ROWS / BM, 512, 0, stream>>>(f0, G0, Hb2, pk, Wp1, b1, Wp2, nullptr,
                                        nullptr, out);
}

// Round 17
// 142.156 us; speedup vs baseline: 1.3533x; 1.0504x over previous
//
#include <hip/hip_runtime.h>

// WL_DiffNet, round 17: round-16 + pk-staging fix.
//   Round-16 bug (rule #21): gl16's GLOBAL source must be per-lane
//   (LDS dest is wave-uniform + lane*16 auto-offset). pk staging had a
//   lane-uniform source -> 64 copies of the same 16B -> garbage indices.
//   Fix: + lane*8 (u16) on the source.
//   Structure: stage F + stage pk->LDS + prefetch B -> barrier0 ->
//   gather -> phase-1a (A_ only, NO barrier) -> barrier1 -> phase-1b.
//   Cross-wave gather/MFMA overlap after barrier0 (m114 co-schedule).
// Math bit-identical to round 15 (absmax must be 0.03125).

#define BB 64
#define NN 512
#define MAXNB 10
#define HH 256
#define ROWS (BB*NN)   // 32768
#define BM 64          // rows per block
#define ZROW 32768     // zero row index in G/Hb2 buffers

typedef _Float16 f16x8 __attribute__((ext_vector_type(8)));
typedef _Float16 h2 __attribute__((ext_vector_type(2)));
typedef __attribute__((ext_vector_type(4))) float f32x4;
typedef unsigned short u16;
typedef unsigned int u32;
typedef __attribute__((address_space(3))) u32 lds_u32;
typedef __attribute__((address_space(1))) const u32 glb_u32;

union U32H2 { u32 u; h2 h; };

__device__ __forceinline__ u16 f2h(float f) {   // rne f32->f16
    union { _Float16 h; u16 u; } v; v.h = (_Float16)f; return v.u;
}
__device__ __forceinline__ void gl16(const u16* g, u16* l) {
    __builtin_amdgcn_global_load_lds((glb_u32*)g, (lds_u32*)l, 16, 0, 0);
}
// XCD-bijective swizzle (nwg % 8 == 0)
__device__ __forceinline__ int xcd_swz(int bid, int nwg) {
    return (bid & 7) * (nwg >> 3) + (bid >> 3);
}

// ---- one-time prep -------------------------------------------------------

__global__ __launch_bounds__(256) void castk(const float* __restrict__ in,
                                             u16* __restrict__ out) {
    int i = blockIdx.x * 256 + threadIdx.x;
    float4 v = ((const float4*)in)[i];
    u32 a = f2h(v.x) | ((u32)f2h(v.y) << 16);
    u32 b = f2h(v.z) | ((u32)f2h(v.w) << 16);
    ((uint2*)out)[i] = make_uint2(a, b);
}

__global__ __launch_bounds__(256) void hb2_kernel(const float* __restrict__ bond,
                                                  const float* __restrict__ W2,
                                                  const float* __restrict__ b2,
                                                  u16* __restrict__ Hb2) {
    int c = threadIdx.x;
    int r0 = blockIdx.x * 8;
    float w[5];
#pragma unroll
    for (int f = 0; f < 5; ++f) w[f] = W2[(size_t)(HH + f) * HH + c];
    float bb = b2[c];
    for (int r = r0; r < r0 + 8; ++r) {
        float s = bb;
#pragma unroll
        for (int f = 0; f < 5; ++f) s += bond[r * 5 + f] * w[f];
        Hb2[(size_t)r * HH + c] = f2h(s);
    }
}

// pk[t] = absrowA | absrowB<<16; invalid -> ZROW (zeroed row)
__global__ __launch_bounds__(256) void pkk(const int* __restrict__ agr,
                                           const int* __restrict__ bgr,
                                           const int* __restrict__ nnb,
                                           u32* __restrict__ pk) {
    int t = blockIdx.x * 256 + threadIdx.x;   // < 327680
    int r = t / 10, k = t - r * 10;
    int brow = (r >> 9) << 9;
    bool valid = (k < nnb[r]);
    u32 pA = valid ? (u32)(brow + agr[t * 2 + 1]) : (u32)ZROW;
    u32 pB = valid ? (u32)(brow + bgr[t * 2 + 1]) : (u32)ZROW;
    pk[t] = pA | (pB << 16);
}

// fragment-major weight pack: Wp[((kt*16+nq)*64+lane)*8 + e] =
//   f16(W[(kt*32 + (lane>>4)*8 + e) * 256 + nq*16 + (lane&15)])
__global__ __launch_bounds__(256) void wpk(const float* __restrict__ W,
                                           u16* __restrict__ Wp) {
    int o = blockIdx.x * 256 + threadIdx.x;
    int e = o & 7, lane = (o >> 3) & 63, nq = (o >> 9) & 15, kt = o >> 13;
    int k = kt * 32 + (lane >> 4) * 8 + e;
    int n = nq * 16 + (lane & 15);
    Wp[o] = f2h(W[(size_t)k * HH + n]);
}

// block 0: zero row ZROW of G0/G1/Hb2; blocks 1..64: zero d_out
__global__ __launch_bounds__(256) void zrow(u16* G0, u16* G1, u16* Hb2,
                                            float* osum) {
    int b = blockIdx.x, t = threadIdx.x;
    if (b == 0) {
        G0[(size_t)ZROW * 256 + t] = 0;
        G1[(size_t)ZROW * 256 + t] = 0;
        Hb2[(size_t)ZROW * 256 + t] = 0;
    } else {
        osum[(b - 1) * 256 + t] = 0.f;
    }
}

// ---- mega: fused gather + [F|N]@W1 + F'@W2a ------------------------------
// 512 thr, 8 waves; wave wc owns cols wc*32..+32, all 64 rows.
// LDS: A_ 32KB (F -> F') + N_ 32KB (N -> G') + pkL 3KB.

__global__ __launch_bounds__(512, 4) void mega(const u16* __restrict__ Fh,
                                               const u16* __restrict__ Gall,
                                               const u16* __restrict__ Hall,
                                               const u32* __restrict__ pk,
                                               const u16* __restrict__ Wp1,
                                               const float* __restrict__ b1,
                                               const u16* __restrict__ Wp2,
                                               u16* __restrict__ Fout,
                                               u16* __restrict__ Gout,
                                               float* __restrict__ osum) {
    __shared__ u16 A_[BM * 256];   // 32KB
    __shared__ u16 N_[BM * 256];   // 32KB
    __shared__ u32 pkL[768];       // 3KB (640 used; staged in 3x1KB gl16)

    int tid = threadIdx.x;
    int base = xcd_swz(blockIdx.x, gridDim.x) * BM;
    int lane = tid & 63, wid = tid >> 6;
    int wc = wid, m = lane & 15, g = lane >> 4;

    // stage F -> A_ (async, pre-swizzled PER-LANE source / linear dest)
#pragma unroll
    for (int q = 0; q < 4; ++q) {
        int c = (wid * 4 + q) * 64 + lane;
        int r = c >> 5, ph = c & 31;
        gl16(Fh + (size_t)(base + r) * 256 + (ph ^ (r & 7)) * 8,
             A_ + (wid * 4 + q) * 512);
    }
    // stage pk slice -> pkL (waves 0..2, 1KB each). Source PER-LANE (+lane*8)!
    if (Wp1 && wid < 3)
        gl16((const u16*)(pk + (size_t)base * 10) + wid * 512 + lane * 8,
             (u16*)pkL + wid * 512);

    uint4 breg[2];
    // prefetch B kt0 (latency absorbed by barrier0's drain)
    {
        const u16* Wp0 = Wp1 ? Wp1 : Wp2;
#pragma unroll
        for (int j = 0; j < 2; ++j)
            breg[j] = *(const uint4*)(Wp0 + ((size_t)(wc * 2 + j) * 64 + lane) * 8);
    }
    __syncthreads();   // barrier0: A_ + pkL staged (one exposed HBM drain)

    if (Wp1) {
        // ---- gather: rows wid*8..+8; pk from LDS; writes N_ --------------
        const uint2* Gb = (const uint2*)Gall;
        const uint2* Hb = (const uint2*)Hall;
        h2 zz = (h2)(_Float16)0;
#pragma unroll
        for (int i = 0; i < 8; ++i) {
            int r = wid * 8 + i;
            h2 accA = zz, accB = zz;
#pragma unroll
            for (int k = 0; k < MAXNB; ++k) {
                u32 p = pkL[r * 10 + k];   // block-local row r
                uint2 ga = Gb[(size_t)(p & 0xffffu) * 64 + lane];
                uint2 hb = Hb[(size_t)(p >> 16) * 64 + lane];
                U32H2 ax{ga.x}, ay{ga.y}, cx{hb.x}, cy{hb.y};
                accA += __builtin_elementwise_max(ax.h + cx.h, zz);
                accB += __builtin_elementwise_max(ay.h + cy.h, zz);
            }
            U32H2 oa, ob; oa.h = accA; ob.h = accB;
            int s16 = (lane >> 1) ^ (r & 7);
            *(uint2*)(N_ + r * 256 + s16 * 8 + (lane & 1) * 4) =
                make_uint2(oa.u, ob.u);
        }

        f32x4 acc[4][2];
#pragma unroll
        for (int mi = 0; mi < 4; ++mi)
#pragma unroll
            for (int j = 0; j < 2; ++j) acc[mi][j] = (f32x4){0.f, 0.f, 0.f, 0.f};

        // ---- phase-1a: kt 0..7 reads A_ ONLY -- NO barrier after gather.
        // Waves desync here: one wave's MFMAs overlap another's gather loads.
        for (int kt = 0; kt < 8; ++kt) {
            f16x8 bcur[2];
            bcur[0] = *(f16x8*)&breg[0];
            bcur[1] = *(f16x8*)&breg[1];
#pragma unroll
            for (int j = 0; j < 2; ++j)
                breg[j] = *(const uint4*)(Wp1 +
                    ((size_t)((kt + 1) * 16 + wc * 2 + j) * 64 + lane) * 8);
            int asl = kt * 4 + g;
            f16x8 af[4];
#pragma unroll
            for (int mi = 0; mi < 4; ++mi) {
                int r = mi * 16 + m;
                af[mi] = *(const f16x8*)(A_ + r * 256 + ((asl ^ (r & 7)) * 8));
            }
#pragma unroll
            for (int mi = 0; mi < 4; ++mi)
#pragma unroll
                for (int j = 0; j < 2; ++j)
                    acc[mi][j] = __builtin_amdgcn_mfma_f32_16x16x32_f16(
                        af[mi], bcur[j], acc[mi][j], 0, 0, 0);
        }
        __syncthreads();   // barrier1: all N_ writes visible

        // ---- phase-1b: kt 8..15 reads N_
        for (int kt = 8; kt < 16; ++kt) {
            f16x8 bcur[2];
            bcur[0] = *(f16x8*)&breg[0];
            bcur[1] = *(f16x8*)&breg[1];
            if (kt < 15) {
#pragma unroll
                for (int j = 0; j < 2; ++j)
                    breg[j] = *(const uint4*)(Wp1 +
                        ((size_t)((kt + 1) * 16 + wc * 2 + j) * 64 + lane) * 8);
            } else if (Gout) {
#pragma unroll
                for (int j = 0; j < 2; ++j)
                    breg[j] = *(const uint4*)(Wp2 +
                        ((size_t)(wc * 2 + j) * 64 + lane) * 8);
            }
            int asl = (kt & 7) * 4 + g;
            f16x8 af[4];
#pragma unroll
            for (int mi = 0; mi < 4; ++mi) {
                int r = mi * 16 + m;
                af[mi] = *(const f16x8*)(N_ + r * 256 + ((asl ^ (r & 7)) * 8));
            }
#pragma unroll
            for (int mi = 0; mi < 4; ++mi)
#pragma unroll
                for (int j = 0; j < 2; ++j)
                    acc[mi][j] = __builtin_amdgcn_mfma_f32_16x16x32_f16(
                        af[mi], bcur[j], acc[mi][j], 0, 0, 0);
        }

        if (osum) {
            // final depth: relu(acc+b1), in-register row-sum, reduce over g,
            // one atomicAdd per (block, col). No F' store, no phase-2.
            int b = base >> 9;
#pragma unroll
            for (int j = 0; j < 2; ++j) {
                int col = wc * 32 + j * 16 + m;
                float bb = b1[col];
                float s = 0.f;
#pragma unroll
                for (int mi = 0; mi < 4; ++mi)
#pragma unroll
                    for (int rr = 0; rr < 4; ++rr)
                        s += fmaxf(acc[mi][j][rr] + bb, 0.f);
                s += __shfl_xor(s, 16);
                s += __shfl_xor(s, 32);
                if (g == 0) atomicAdd(osum + b * 256 + col, s);
            }
            return;
        }

        __syncthreads();   // B2: all waves done reading A_/N_

        // F' = relu(acc+b1) -> A_ (F dead)
#pragma unroll
        for (int mi = 0; mi < 4; ++mi)
#pragma unroll
            for (int j = 0; j < 2; ++j) {
                int col = wc * 32 + j * 16 + m;
                float bb = b1[col];
#pragma unroll
                for (int rr = 0; rr < 4; ++rr) {
                    int r = mi * 16 + g * 4 + rr;
                    A_[r * 256 + ((col >> 3) ^ (r & 7)) * 8 + (col & 7)] =
                        f2h(fmaxf(acc[mi][j][rr] + bb, 0.f));
                }
            }
        __syncthreads();   // B3: F' visible

        // coalesced F' store
#pragma unroll
        for (int i = 0; i < 4; ++i) {
            int c = tid + i * 512;
            int r = c >> 5, ph = c & 31;
            uint4 v = ((const uint4*)A_)[r * 32 + ph];
            ((uint4*)(Fout + (size_t)(base + r) * 256))[ph ^ (r & 7)] = v;
        }
    }
    // (skip-mode: barrier0 already done; breg holds Wp2 kt0)

    if (!Gout) return;

    // phase-2: G' = A_(F' or F) @ W2a, K=256, 8 kt, barrier-free
    f32x4 gacc[4][2];
#pragma unroll
    for (int mi = 0; mi < 4; ++mi)
#pragma unroll
        for (int j = 0; j < 2; ++j) gacc[mi][j] = (f32x4){0.f, 0.f, 0.f, 0.f};

    for (int kt = 0; kt < 8; ++kt) {
        f16x8 bcur[2];
        bcur[0] = *(f16x8*)&breg[0];
        bcur[1] = *(f16x8*)&breg[1];
        if (kt < 7) {
#pragma unroll
            for (int j = 0; j < 2; ++j)
                breg[j] = *(const uint4*)(Wp2 +
                    ((size_t)((kt + 1) * 16 + wc * 2 + j) * 64 + lane) * 8);
        }
        int asl = kt * 4 + g;
        f16x8 af[4];
#pragma unroll
        for (int mi = 0; mi < 4; ++mi) {
            int r = mi * 16 + m;
            af[mi] = *(const f16x8*)(A_ + r * 256 + ((asl ^ (r & 7)) * 8));
        }
#pragma unroll
        for (int mi = 0; mi < 4; ++mi)
#pragma unroll
            for (int j = 0; j < 2; ++j)
                gacc[mi][j] = __builtin_amdgcn_mfma_f32_16x16x32_f16(
                    af[mi], bcur[j], gacc[mi][j], 0, 0, 0);
    }

    // G' -> N_ bounce (N dead), then coalesced store
#pragma unroll
    for (int mi = 0; mi < 4; ++mi)
#pragma unroll
        for (int j = 0; j < 2; ++j) {
            int col = wc * 32 + j * 16 + m;
#pragma unroll
            for (int rr = 0; rr < 4; ++rr) {
                int r = mi * 16 + g * 4 + rr;
                N_[r * 256 + ((col >> 3) ^ (r & 7)) * 8 + (col & 7)] =
                    f2h(gacc[mi][j][rr]);
            }
        }
    __syncthreads();   // B4: G' visible
#pragma unroll
    for (int i = 0; i < 4; ++i) {
        int c = tid + i * 512;
        int r = c >> 5, ph = c & 31;
        uint4 v = ((const uint4*)N_)[r * 32 + ph];
        ((uint4*)(Gout + (size_t)(base + r) * 256))[ph ^ (r & 7)] = v;
    }
}

extern "C" void kernel_launch(void* const* d_in, const int* in_sizes, int n_in,
                              void* d_out, int out_size, void* d_ws, size_t ws_size,
                              hipStream_t stream) {
    const float* input_bond    = (const float*)d_in[1];
    const int*   atom_graph    = (const int*)d_in[2];
    const int*   bond_graph    = (const int*)d_in[3];
    const int*   num_nbs       = (const int*)d_in[4];
    const float* atom_features = (const float*)d_in[5];
    const float* W2 = (const float*)d_in[6];
    const float* b2 = (const float*)d_in[7];
    const float* W1 = (const float*)d_in[8];
    const float* b1 = (const float*)d_in[9];
    float* out = (float*)d_out;

    char* w = (char*)d_ws;
    u16* f0  = (u16*)w;                          // 16MB
    u16* f1  = (u16*)(w + ((size_t)16 << 20));   // 16MB
    u16* G0  = (u16*)(w + ((size_t)32 << 20));   // 16MB + zero row
    u16* G1  = (u16*)(w + ((size_t)49 << 20));   // 16MB + zero row
    u16* Hb2 = (u16*)(w + ((size_t)66 << 20));   // 16MB + zero row
    u16* Wp1 = (u16*)(w + ((size_t)83 << 20));            // 256KB
    u16* Wp2 = (u16*)(w + ((size_t)83 << 20) + (512 << 10)); // 128KB
    u32* pk  = (u32*)(w + ((size_t)84 << 20));   // 1.25MB

    castk<<<ROWS * HH / 1024, 256, 0, stream>>>(atom_features, f0);
    hb2_kernel<<<ROWS / 8, 256, 0, stream>>>(input_bond, W2, b2, Hb2);
    pkk<<<ROWS * MAXNB / 256, 256, 0, stream>>>(atom_graph, bond_graph, num_nbs, pk);
    wpk<<<512, 256, 0, stream>>>(W1, Wp1);   // kt 0..15
    wpk<<<256, 256, 0, stream>>>(W2, Wp2);   // kt 0..7 (W2a part)
    zrow<<<65, 256, 0, stream>>>(G0, G1, Hb2, out);

    // G0 = F0 @ W2a  (skip-mode)
    mega<<<ROWS / BM, 512, 0, stream>>>(f0, nullptr, nullptr, nullptr,
                                        nullptr, nullptr, Wp2, nullptr, G0,
                                        nullptr);
    // depth 0..2 (G ping-pong; final depth: fused row-sum -> d_out)
    mega<<<ROWS / BM, 512, 0, stream>>>(f0, G0, Hb2, pk, Wp1, b1, Wp2, f1, G1,
                                        nullptr);
    mega<<<ROWS / BM, 512, 0, stream>>>(f1, G1, Hb2, pk, Wp1, b1, Wp2, f0, G0,
                                        nullptr);
    mega<<<ROWS / BM, 512, 0, stream>>>(f0, G0, Hb2, pk, Wp1, b1, Wp2, nullptr,
                                        nullptr, out);
}